// Round 3
// baseline (772.680 us; speedup 1.0000x reference)
//
#include <hip/hip_runtime.h>
#include <hip/hip_bf16.h>
#include <stdint.h>

// Problem constants (from reference)
#define N_NODES 30000
#define E_EDGES 240000
#define NGRAPH  16
#define D1      256
#define D2      512
#define D3      1024
#define DOUT    1024
#define M_PAD   30080   // 235 * 128, padded row count for GEMM tiles
#define CAP     40      // max in-degree (Poisson(8): P(>=40) negligible)

typedef unsigned short ushort_t;
typedef short short8 __attribute__((ext_vector_type(8)));
typedef float f32x4 __attribute__((ext_vector_type(4)));

__device__ __forceinline__ float bf2f(ushort_t u) {
    union { unsigned int i; float f; } v; v.i = ((unsigned int)u) << 16; return v.f;
}
__device__ __forceinline__ ushort_t f2bf(float x) {
    union { float f; unsigned int i; } v; v.f = x;
    unsigned int r = v.i + 0x7fffu + ((v.i >> 16) & 1u);   // RNE
    return (ushort_t)(r >> 16);
}

// ---------------- runtime dtype detection ----------------
// flags[0] = 1 if float arrays are bf16, 0 if fp32
// flags[1] = 1 if index arrays are int64, 0 if int32
__global__ void k_detect(const void* w1, const void* ei, int* flags) {
    if (threadIdx.x != 0 || blockIdx.x != 0) return;
    // If W1 (256 Xavier values, |v|<=0.153) is bf16, ushorts at EVEN indices are
    // genuine values. If it's fp32, even ushorts are low mantissa halves (random).
    const ushort_t* h = (const ushort_t*)w1;
    int isbf16 = 1;
    for (int i = 0; i < 128; i += 2) {
        float v = fabsf(bf2f(h[i]));
        if (!(v <= 0.25f)) { isbf16 = 0; break; }   // NaN also fails -> fp32
    }
    // If edge_index is int64 (values < 2^31), odd int32 words are all zero.
    const int* e = (const int*)ei;
    int isi64 = 1;
    for (int i = 1; i < 128; i += 2) {
        if (e[i] != 0) { isi64 = 0; break; }
    }
    flags[0] = isbf16;
    flags[1] = isi64;
}

// ---------------- canonicalization ----------------
__global__ void k_cvt_f32(const void* in, float* out, int n, const int* flags) {
    int i = blockIdx.x * 256 + threadIdx.x;
    if (i >= n) return;
    out[i] = flags[0] ? bf2f(((const ushort_t*)in)[i]) : ((const float*)in)[i];
}

__global__ void k_cvt_idx(const void* in, int* out, int n, const int* flags) {
    int i = blockIdx.x * 256 + threadIdx.x;
    if (i >= n) return;
    out[i] = flags[1] ? (int)((const long long*)in)[i] : ((const int*)in)[i];
}

// transpose (R x C -> C x R) + convert to bf16; dims multiples of 32
__global__ void k_transpose_cvt(const void* in, ushort_t* out, int R, int C, const int* flags) {
    __shared__ ushort_t tile[32][33];
    int tx = threadIdx.x, ty = threadIdx.y;
    int c0 = blockIdx.x * 32, r0 = blockIdx.y * 32;
    int isbf = flags[0];
    for (int i = ty; i < 32; i += 8) {
        size_t idx = (size_t)(r0 + i) * C + c0 + tx;
        tile[i][tx] = isbf ? ((const ushort_t*)in)[idx] : f2bf(((const float*)in)[idx]);
    }
    __syncthreads();
    for (int i = ty; i < 32; i += 8) out[(size_t)(c0 + i) * R + r0 + tx] = tile[tx][i];
}

// ---------------- setup kernels ----------------
__global__ void k_init(float* deg, int* slotcnt, float* pooled, float* cntg) {
    int i = blockIdx.x * 256 + threadIdx.x;
    if (i < N_NODES) { deg[i] = 1.0f; slotcnt[i] = 0; }  // self-loop => deg starts at 1
    if (i < NGRAPH * DOUT) pooled[i] = 0.0f;
    if (i < NGRAPH) cntg[i] = 0.0f;
}

__global__ void k_edge_count(const int* eis, const int* eid, float* deg, int* slotcnt, int* slots) {
    int e = blockIdx.x * 256 + threadIdx.x;
    if (e >= E_EDGES) return;
    int s = eis[e], d = eid[e];
    if ((unsigned)s >= N_NODES || (unsigned)d >= N_NODES) return;
    atomicAdd(&deg[d], 1.0f);
    int pos = atomicAdd(&slotcnt[d], 1);
    if (pos < CAP) slots[d * CAP + pos] = s;
}

__global__ void k_node(const float* xf, const int* batch, const float* deg,
                       float* dis, float* s1, float* cntg) {
    int i = blockIdx.x * 256 + threadIdx.x;
    if (i >= N_NODES) return;
    float dg = deg[i];
    dis[i] = rsqrtf(dg);
    s1[i] = xf[i] / dg;                    // self-loop term, norm = 1/deg
    int g = batch[i]; g = g < 0 ? 0 : (g > NGRAPH - 1 ? NGRAPH - 1 : g);
    atomicAdd(&cntg[g], 1.0f);
}

// scalar aggregation of x (layer-1 linear input is 1-dim)
__global__ void k_edge_s1(const int* eis, const int* eid, const float* xf, const float* dis, float* s1) {
    int e = blockIdx.x * 256 + threadIdx.x;
    if (e >= E_EDGES) return;
    int s = eis[e], d = eid[e];
    if ((unsigned)s >= N_NODES || (unsigned)d >= N_NODES) return;
    atomicAdd(&s1[d], xf[s] * dis[s] * dis[d]);
}

// ---------------- fused layer-1 + layer-2 aggregation ----------------
// a2[d][c] = (1/deg_d)*relu(s1[d]*W1[c]+b1[c]) + sum_s dis[s]*dis[d]*relu(s1[s]*W1[c]+b1[c])
__global__ void k_agg1(const float* s1, const float* W1f, const float* b1f,
                       ushort_t* a2, const int* slots, const int* slotcnt, const float* dis) {
    int node = blockIdx.x * 2 + (threadIdx.x >> 7);   // 2 nodes/block, 128 thr/node
    int c2 = (threadIdx.x & 127) * 2;                 // 2 channels/thread
    if (node >= N_NODES) return;
    float w0 = W1f[c2], w1 = W1f[c2 + 1];
    float bb0 = b1f[c2], bb1 = b1f[c2 + 1];
    float di = dis[node];
    int cnt = slotcnt[node]; cnt = cnt < CAP ? cnt : CAP;
    float sv = s1[node];
    float wsl = di * di;
    float a0 = wsl * fmaxf(sv * w0 + bb0, 0.0f);
    float a1 = wsl * fmaxf(sv * w1 + bb1, 0.0f);
    for (int k = 0; k < cnt; k++) {
        int s = slots[node * CAP + k];
        float ss = s1[s];
        float wn = dis[s] * di;
        a0 += wn * fmaxf(ss * w0 + bb0, 0.0f);
        a1 += wn * fmaxf(ss * w1 + bb1, 0.0f);
    }
    unsigned int o = (unsigned int)f2bf(a0) | ((unsigned int)f2bf(a1) << 16);
    *(unsigned int*)&a2[(size_t)node * D1 + c2] = o;
}

// ---------------- layer-3 aggregation: a3 = A_hat * h2  (512 ch) ----------------
__global__ void k_agg2(const ushort_t* h, ushort_t* out, const int* slots,
                       const int* slotcnt, const float* dis) {
    int node = blockIdx.x;                 // 1 node/block, 256 threads
    int c2 = threadIdx.x * 2;              // 2 ch/thread -> 512
    float di = dis[node];
    int cnt = slotcnt[node]; cnt = cnt < CAP ? cnt : CAP;
    float w = di * di;
    unsigned int p = *(const unsigned int*)&h[(size_t)node * D2 + c2];
    float a0 = w * bf2f((ushort_t)(p & 0xffffu));
    float a1 = w * bf2f((ushort_t)(p >> 16));
    for (int k = 0; k < cnt; k++) {
        int s = slots[node * CAP + k];
        float ws = dis[s] * di;
        unsigned int q = *(const unsigned int*)&h[(size_t)s * D2 + c2];
        a0 += ws * bf2f((ushort_t)(q & 0xffffu));
        a1 += ws * bf2f((ushort_t)(q >> 16));
    }
    unsigned int o = (unsigned int)f2bf(a0) | ((unsigned int)f2bf(a1) << 16);
    *(unsigned int*)&out[(size_t)node * D2 + c2] = o;
}

// ---------------- MFMA bf16 GEMM:  C = relu(A @ B + bias) ----------------
// A: M_PAD x K (row-major bf16), Bt: N x K (row-major bf16), bias fp32
__global__ __launch_bounds__(256) void k_gemm(const ushort_t* A, const ushort_t* Bt,
                                              const float* bias, ushort_t* Cmat,
                                              int K, int Ncols) {
    __shared__ __align__(16) ushort_t As[128 * 32];
    __shared__ __align__(16) ushort_t Bs[128 * 32];
    int tid = threadIdx.x;
    int bm0 = blockIdx.x * 128, bn0 = blockIdx.y * 128;
    int wave = tid >> 6, lane = tid & 63;
    int wm = (wave & 1) * 64, wn = (wave >> 1) * 64;
    int l15 = lane & 15, quad = lane >> 4;

    f32x4 acc[4][4];
    for (int a = 0; a < 4; a++)
        for (int b = 0; b < 4; b++)
            acc[a][b] = (f32x4){0.f, 0.f, 0.f, 0.f};

    int m1 = tid >> 2, k1 = (tid & 3) << 3;
    int m2 = (tid + 256) >> 2, k2 = ((tid + 256) & 3) << 3;

    for (int kt = 0; kt < K; kt += 32) {
        *(uint4*)&As[m1 * 32 + k1] = *(const uint4*)&A[(size_t)(bm0 + m1) * K + kt + k1];
        *(uint4*)&As[m2 * 32 + k2] = *(const uint4*)&A[(size_t)(bm0 + m2) * K + kt + k2];
        *(uint4*)&Bs[m1 * 32 + k1] = *(const uint4*)&Bt[(size_t)(bn0 + m1) * K + kt + k1];
        *(uint4*)&Bs[m2 * 32 + k2] = *(const uint4*)&Bt[(size_t)(bn0 + m2) * K + kt + k2];
        __syncthreads();

        short8 af[4], bfr[4];
        for (int im = 0; im < 4; im++)
            af[im] = *(const short8*)&As[(wm + im * 16 + l15) * 32 + quad * 8];
        for (int in = 0; in < 4; in++)
            bfr[in] = *(const short8*)&Bs[(wn + in * 16 + l15) * 32 + quad * 8];
        for (int im = 0; im < 4; im++)
            for (int in = 0; in < 4; in++)
                acc[im][in] = __builtin_amdgcn_mfma_f32_16x16x32_bf16(af[im], bfr[in], acc[im][in], 0, 0, 0);
        __syncthreads();
    }

    // epilogue: C/D layout col=lane&15, row=quad*4+r  [m89-verified]
    for (int im = 0; im < 4; im++) {
        int row = bm0 + wm + im * 16 + quad * 4;
        for (int in = 0; in < 4; in++) {
            int col = bn0 + wn + in * 16 + l15;
            float bv = bias[col];
            for (int r = 0; r < 4; r++) {
                float v = acc[im][in][r] + bv;
                v = v > 0.0f ? v : 0.0f;
                Cmat[(size_t)(row + r) * Ncols + col] = f2bf(v);
            }
        }
    }
}

// ---------------- GEMM2 with fused mean-pool accumulation ----------------
__global__ __launch_bounds__(256) void k_gemm_pool(const ushort_t* A, const ushort_t* Bt,
                                                   const float* bias, const int* batch,
                                                   float* pooled, int K) {
    __shared__ __align__(16) ushort_t As[128 * 32];
    __shared__ __align__(16) ushort_t Bs[128 * 32];
    __shared__ float pl[NGRAPH * 128];
    __shared__ int gtile[128];
    int tid = threadIdx.x;
    int bm0 = blockIdx.x * 128, bn0 = blockIdx.y * 128;
    int wave = tid >> 6, lane = tid & 63;
    int wm = (wave & 1) * 64, wn = (wave >> 1) * 64;
    int l15 = lane & 15, quad = lane >> 4;

    for (int i = tid; i < NGRAPH * 128; i += 256) pl[i] = 0.0f;
    if (tid < 128) {
        int r = bm0 + tid; if (r > N_NODES - 1) r = N_NODES - 1;
        int g = batch[r]; g = g < 0 ? 0 : (g > NGRAPH - 1 ? NGRAPH - 1 : g);
        gtile[tid] = g;
    }

    f32x4 acc[4][4];
    for (int a = 0; a < 4; a++)
        for (int b = 0; b < 4; b++)
            acc[a][b] = (f32x4){0.f, 0.f, 0.f, 0.f};

    int m1 = tid >> 2, k1 = (tid & 3) << 3;
    int m2 = (tid + 256) >> 2, k2 = ((tid + 256) & 3) << 3;

    for (int kt = 0; kt < K; kt += 32) {
        *(uint4*)&As[m1 * 32 + k1] = *(const uint4*)&A[(size_t)(bm0 + m1) * K + kt + k1];
        *(uint4*)&As[m2 * 32 + k2] = *(const uint4*)&A[(size_t)(bm0 + m2) * K + kt + k2];
        *(uint4*)&Bs[m1 * 32 + k1] = *(const uint4*)&Bt[(size_t)(bn0 + m1) * K + kt + k1];
        *(uint4*)&Bs[m2 * 32 + k2] = *(const uint4*)&Bt[(size_t)(bn0 + m2) * K + kt + k2];
        __syncthreads();

        short8 af[4], bfr[4];
        for (int im = 0; im < 4; im++)
            af[im] = *(const short8*)&As[(wm + im * 16 + l15) * 32 + quad * 8];
        for (int in = 0; in < 4; in++)
            bfr[in] = *(const short8*)&Bs[(wn + in * 16 + l15) * 32 + quad * 8];
        for (int im = 0; im < 4; im++)
            for (int in = 0; in < 4; in++)
                acc[im][in] = __builtin_amdgcn_mfma_f32_16x16x32_bf16(af[im], bfr[in], acc[im][in], 0, 0, 0);
        __syncthreads();
    }

    // epilogue: bias + relu, reduce rows by graph into LDS pool table
    for (int im = 0; im < 4; im++) {
        int rl = wm + im * 16 + quad * 4;
        for (int in = 0; in < 4; in++) {
            int cl = wn + in * 16 + l15;
            float bv = bias[bn0 + cl];
            float vsum = 0.0f;
            int gprev = gtile[rl];
            for (int r = 0; r < 4; r++) {
                int row = bm0 + rl + r;
                float v = (row < N_NODES) ? fmaxf(acc[im][in][r] + bv, 0.0f) : 0.0f;
                int g = gtile[rl + r];
                if (g != gprev) {
                    atomicAdd(&pl[gprev * 128 + cl], vsum);
                    vsum = 0.0f; gprev = g;
                }
                vsum += v;
            }
            atomicAdd(&pl[gprev * 128 + cl], vsum);
        }
    }
    __syncthreads();

    int gmin = gtile[0], gmax = gtile[127];
    int span = (gmax - gmin + 1) * 128;
    for (int idx = tid; idx < span; idx += 256) {
        int g = gmin + (idx >> 7), cl = idx & 127;
        float v = pl[g * 128 + cl];
        if (v != 0.0f) atomicAdd(&pooled[g * DOUT + bn0 + cl], v);
    }
}

// ---------------- tail ----------------
__global__ void k_pooldiv(float* pooled, const float* cntg) {
    int i = blockIdx.x * 256 + threadIdx.x;
    if (i >= NGRAPH * DOUT) return;
    int g = i >> 10;
    float c = cntg[g]; c = c > 1.0f ? c : 1.0f;
    pooled[i] = pooled[i] / c;
}

// out[g][o] = pooled[g] . Wo[:,o] + bo[o]; output format per flags[0]
__global__ void k_out(const float* pooled, const float* Wof, const float* bof,
                      void* out, const int* flags) {
    int g = blockIdx.x;
    int o = blockIdx.y * 256 + threadIdx.x;
    float acc = bof[o];
    const float* pr = pooled + g * D3;
    for (int k = 0; k < D3; k++)
        acc += pr[k] * Wof[(size_t)k * DOUT + o];
    size_t idx = (size_t)g * DOUT + o;
    if (flags[0]) ((ushort_t*)out)[idx] = f2bf(acc);
    else          ((float*)out)[idx] = acc;
}

// ---------------- launch ----------------
extern "C" void kernel_launch(void* const* d_in, const int* in_sizes, int n_in,
                              void* d_out, int out_size, void* d_ws, size_t ws_size,
                              hipStream_t stream) {
    const void* x_raw  = d_in[0];
    const void* ei_raw = d_in[1];
    const void* b_raw  = d_in[2];
    const void* W1_raw = d_in[3];
    const void* b1_raw = d_in[4];
    const void* W2_raw = d_in[5];
    const void* b2_raw = d_in[6];
    const void* W3_raw = d_in[7];
    const void* b3_raw = d_in[8];
    const void* Wo_raw = d_in[9];
    const void* bo_raw = d_in[10];

    char* w = (char*)d_ws;
    size_t off = 0;
    auto alloc = [&](size_t b) { size_t o = off; off += (b + 255) & ~(size_t)255; return o; };
    int*   flags   = (int*)  (w + alloc(256));
    float* xf      = (float*)(w + alloc((size_t)N_NODES * 4));
    int*   ei32    = (int*)  (w + alloc((size_t)2 * E_EDGES * 4));   // [src | dst]
    int*   batch32 = (int*)  (w + alloc((size_t)N_NODES * 4));
    float* W1f     = (float*)(w + alloc(D1 * 4));
    float* b1f     = (float*)(w + alloc(D1 * 4));
    float* b2f     = (float*)(w + alloc(D2 * 4));
    float* b3f     = (float*)(w + alloc(D3 * 4));
    float* Wof     = (float*)(w + alloc((size_t)D3 * DOUT * 4));
    float* bof     = (float*)(w + alloc(DOUT * 4));
    float* deg     = (float*)(w + alloc((size_t)N_NODES * 4));
    float* dis     = (float*)(w + alloc((size_t)N_NODES * 4));
    float* s1      = (float*)(w + alloc((size_t)N_NODES * 4));
    float* cntg    = (float*)(w + alloc(64));
    float* pooled  = (float*)(w + alloc((size_t)NGRAPH * DOUT * 4));
    int*   slotcnt = (int*)  (w + alloc((size_t)N_NODES * 4));
    int*   slots   = (int*)  (w + alloc((size_t)N_NODES * CAP * 4));
    ushort_t* Wt2  = (ushort_t*)(w + alloc((size_t)D2 * D1 * 2));
    ushort_t* Wt3  = (ushort_t*)(w + alloc((size_t)D3 * D2 * 2));
    // slabA: a2 (M_PAD x 256) first half; a3 (M_PAD x 512) reuses whole slab after a2 dies
    ushort_t* slabA = (ushort_t*)(w + alloc((size_t)M_PAD * D2 * 2));
    ushort_t* a2 = slabA;
    ushort_t* a3 = slabA;
    ushort_t* h2   = (ushort_t*)(w + alloc((size_t)M_PAD * D2 * 2));

    int nb_n = (N_NODES + 255) / 256;
    int nb_e = (E_EDGES + 255) / 256;

    k_detect<<<1, 64, 0, stream>>>(W1_raw, ei_raw, flags);

    // canonicalize inputs
    k_cvt_f32<<<nb_n, 256, 0, stream>>>(x_raw, xf, N_NODES, flags);
    k_cvt_idx<<<(2 * E_EDGES + 255) / 256, 256, 0, stream>>>(ei_raw, ei32, 2 * E_EDGES, flags);
    k_cvt_idx<<<nb_n, 256, 0, stream>>>(b_raw, batch32, N_NODES, flags);
    k_cvt_f32<<<1, 256, 0, stream>>>(W1_raw, W1f, D1, flags);
    k_cvt_f32<<<1, 256, 0, stream>>>(b1_raw, b1f, D1, flags);
    k_cvt_f32<<<2, 256, 0, stream>>>(b2_raw, b2f, D2, flags);
    k_cvt_f32<<<4, 256, 0, stream>>>(b3_raw, b3f, D3, flags);
    k_cvt_f32<<<(D3 * DOUT + 255) / 256, 256, 0, stream>>>(Wo_raw, Wof, D3 * DOUT, flags);
    k_cvt_f32<<<4, 256, 0, stream>>>(bo_raw, bof, DOUT, flags);
    k_transpose_cvt<<<dim3(D2 / 32, D1 / 32), dim3(32, 8), 0, stream>>>(W2_raw, Wt2, D1, D2, flags);
    k_transpose_cvt<<<dim3(D3 / 32, D2 / 32), dim3(32, 8), 0, stream>>>(W3_raw, Wt3, D2, D3, flags);

    // graph preprocessing
    k_init<<<nb_n, 256, 0, stream>>>(deg, slotcnt, pooled, cntg);
    k_edge_count<<<nb_e, 256, 0, stream>>>(ei32, ei32 + E_EDGES, deg, slotcnt, slots);
    k_node<<<nb_n, 256, 0, stream>>>(xf, batch32, deg, dis, s1, cntg);
    k_edge_s1<<<nb_e, 256, 0, stream>>>(ei32, ei32 + E_EDGES, xf, dis, s1);

    // layer pipeline
    k_agg1<<<N_NODES / 2, 256, 0, stream>>>(s1, W1f, b1f, a2, slots, slotcnt, dis);
    k_gemm<<<dim3(M_PAD / 128, D2 / 128), 256, 0, stream>>>(a2, Wt2, b2f, h2, D1, D2);
    k_agg2<<<N_NODES, 256, 0, stream>>>(h2, a3, slots, slotcnt, dis);
    k_gemm_pool<<<dim3(M_PAD / 128, D3 / 128), 256, 0, stream>>>(a3, Wt3, b3f, batch32, pooled, D2);

    k_pooldiv<<<(NGRAPH * DOUT + 255) / 256, 256, 0, stream>>>(pooled, cntg);
    k_out<<<dim3(NGRAPH, DOUT / 256), 256, 0, stream>>>(pooled, Wof, bof, d_out, flags);
}

// Round 4
// 371.460 us; speedup vs baseline: 2.0801x; 2.0801x over previous
//
#include <hip/hip_runtime.h>
#include <hip/hip_bf16.h>
#include <stdint.h>

// Problem constants (from reference)
#define N_NODES 30000
#define E_EDGES 240000
#define NGRAPH  16
#define D1      256
#define D2      512
#define D3      1024
#define DOUT    1024
#define M_PAD   30080   // 235 * 128, padded row count for GEMM tiles
#define CAP     40      // max in-degree (Poisson(8): P(>=40) negligible)

typedef unsigned short ushort_t;
typedef short short8 __attribute__((ext_vector_type(8)));
typedef float f32x4 __attribute__((ext_vector_type(4)));

__device__ __forceinline__ float bf2f(ushort_t u) {
    union { unsigned int i; float f; } v; v.i = ((unsigned int)u) << 16; return v.f;
}
__device__ __forceinline__ ushort_t f2bf(float x) {
    union { float f; unsigned int i; } v; v.f = x;
    unsigned int r = v.i + 0x7fffu + ((v.i >> 16) & 1u);   // RNE
    return (ushort_t)(r >> 16);
}

// ---------------- runtime dtype detection ----------------
// flags[0] = 1 if float arrays are bf16, 0 if fp32
// flags[1] = 1 if index arrays are int64, 0 if int32
__global__ void k_detect(const void* w1, const void* ei, int* flags) {
    if (threadIdx.x != 0 || blockIdx.x != 0) return;
    const ushort_t* h = (const ushort_t*)w1;
    int isbf16 = 1;
    for (int i = 0; i < 128; i += 2) {
        float v = fabsf(bf2f(h[i]));
        if (!(v <= 0.25f)) { isbf16 = 0; break; }
    }
    const int* e = (const int*)ei;
    int isi64 = 1;
    for (int i = 1; i < 128; i += 2) {
        if (e[i] != 0) { isi64 = 0; break; }
    }
    flags[0] = isbf16;
    flags[1] = isi64;
}

// ---------------- canonicalization ----------------
__global__ void k_cvt_f32(const void* in, float* out, int n, const int* flags) {
    int i = blockIdx.x * 256 + threadIdx.x;
    if (i >= n) return;
    out[i] = flags[0] ? bf2f(((const ushort_t*)in)[i]) : ((const float*)in)[i];
}

__global__ void k_cvt_idx(const void* in, int* out, int n, const int* flags) {
    int i = blockIdx.x * 256 + threadIdx.x;
    if (i >= n) return;
    out[i] = flags[1] ? (int)((const long long*)in)[i] : ((const int*)in)[i];
}

// merged small-array conversion: W1(256), b1(256), b2(512), b3(1024), bo(1024) = 3072
__global__ void k_cvt_small(const void* w1, const void* b1, const void* b2,
                            const void* b3, const void* bo,
                            float* W1f, float* b1f, float* b2f, float* b3f, float* bof,
                            const int* flags) {
    int i = blockIdx.x * 256 + threadIdx.x;
    const void* src; float* dst; int idx;
    if      (i < 256)  { src = w1; dst = W1f; idx = i; }
    else if (i < 512)  { src = b1; dst = b1f; idx = i - 256; }
    else if (i < 1024) { src = b2; dst = b2f; idx = i - 512; }
    else if (i < 2048) { src = b3; dst = b3f; idx = i - 1024; }
    else               { src = bo; dst = bof; idx = i - 2048; }
    dst[idx] = flags[0] ? bf2f(((const ushort_t*)src)[idx]) : ((const float*)src)[idx];
}

// transpose (R x C -> C x R) + convert to bf16; dims multiples of 32
__global__ void k_transpose_cvt(const void* in, ushort_t* out, int R, int C, const int* flags) {
    __shared__ ushort_t tile[32][33];
    int tx = threadIdx.x, ty = threadIdx.y;
    int c0 = blockIdx.x * 32, r0 = blockIdx.y * 32;
    int isbf = flags[0];
    for (int i = ty; i < 32; i += 8) {
        size_t idx = (size_t)(r0 + i) * C + c0 + tx;
        tile[i][tx] = isbf ? ((const ushort_t*)in)[idx] : f2bf(((const float*)in)[idx]);
    }
    __syncthreads();
    for (int i = ty; i < 32; i += 8) out[(size_t)(c0 + i) * R + r0 + tx] = tile[tx][i];
}

// ---------------- setup kernels ----------------
__global__ void k_init(int* slotcnt, float* pooled) {
    int i = blockIdx.x * 256 + threadIdx.x;
    if (i < N_NODES) slotcnt[i] = 0;
    if (i < NGRAPH * DOUT) pooled[i] = 0.0f;
}

// build bucketed adjacency; slotcnt counts ALL in-edges (deg = 1 + slotcnt)
__global__ void k_edge_count(const int* eis, const int* eid, int* slotcnt, int* slots) {
    int e = blockIdx.x * 256 + threadIdx.x;
    if (e >= E_EDGES) return;
    int s = eis[e], d = eid[e];
    if ((unsigned)s >= N_NODES || (unsigned)d >= N_NODES) return;
    int pos = atomicAdd(&slotcnt[d], 1);
    if (pos < CAP) slots[d * CAP + pos] = s;
}

// dis = rsqrt(1 + in-degree)
__global__ void k_node(const int* slotcnt, float* dis) {
    int i = blockIdx.x * 256 + threadIdx.x;
    if (i >= N_NODES) return;
    dis[i] = rsqrtf(1.0f + (float)slotcnt[i]);
}

// graph node counts via binary search on sorted batch (zero atomics)
__global__ void k_cnt(const int* batch, float* cntg) {
    int g = threadIdx.x;            // 0..15
    if (g >= NGRAPH) return;
    // lower_bound(g) and lower_bound(g+1)
    int lo0 = 0, hi0 = N_NODES;
    while (lo0 < hi0) { int m = (lo0 + hi0) >> 1; if (batch[m] < g) lo0 = m + 1; else hi0 = m; }
    int lo1 = lo0, hi1 = N_NODES;
    while (lo1 < hi1) { int m = (lo1 + hi1) >> 1; if (batch[m] < g + 1) lo1 = m + 1; else hi1 = m; }
    cntg[g] = (float)(lo1 - lo0);
}

// s1[d] = x[d]*dis[d]^2 + dis[d] * sum_s x[s]*dis[s]   (gather, no atomics)
__global__ void k_s1(const float* xf, const float* dis, const int* slots,
                     const int* slotcnt, float* s1) {
    int d = blockIdx.x * 256 + threadIdx.x;
    if (d >= N_NODES) return;
    float di = dis[d];
    int cnt = slotcnt[d]; cnt = cnt < CAP ? cnt : CAP;
    float acc = xf[d] * di;                 // will be scaled by di below (self: x*di*di)
    for (int k = 0; k < cnt; k++) {
        int s = slots[d * CAP + k];
        acc += xf[s] * dis[s];
    }
    s1[d] = acc * di;
}

// ---------------- fused layer-1 + layer-2 aggregation ----------------
// a2[d][c] = dis[d]^2*relu(s1[d]*W1[c]+b1[c]) + sum_s dis[s]*dis[d]*relu(s1[s]*W1[c]+b1[c])
__global__ void k_agg1(const float* s1, const float* W1f, const float* b1f,
                       ushort_t* a2, const int* slots, const int* slotcnt, const float* dis) {
    int node = blockIdx.x * 2 + (threadIdx.x >> 7);   // 2 nodes/block, 128 thr/node
    int c2 = (threadIdx.x & 127) * 2;                 // 2 channels/thread
    if (node >= N_NODES) return;
    float w0 = W1f[c2], w1 = W1f[c2 + 1];
    float bb0 = b1f[c2], bb1 = b1f[c2 + 1];
    float di = dis[node];
    int cnt = slotcnt[node]; cnt = cnt < CAP ? cnt : CAP;
    float sv = s1[node];
    float wsl = di * di;
    float a0 = wsl * fmaxf(sv * w0 + bb0, 0.0f);
    float a1 = wsl * fmaxf(sv * w1 + bb1, 0.0f);
    for (int k = 0; k < cnt; k++) {
        int s = slots[node * CAP + k];
        float ss = s1[s];
        float wn = dis[s] * di;
        a0 += wn * fmaxf(ss * w0 + bb0, 0.0f);
        a1 += wn * fmaxf(ss * w1 + bb1, 0.0f);
    }
    unsigned int o = (unsigned int)f2bf(a0) | ((unsigned int)f2bf(a1) << 16);
    *(unsigned int*)&a2[(size_t)node * D1 + c2] = o;
}

// ---------------- layer-3 aggregation: a3 = A_hat * h2  (512 ch) ----------------
__global__ void k_agg2(const ushort_t* h, ushort_t* out, const int* slots,
                       const int* slotcnt, const float* dis) {
    int node = blockIdx.x;                 // 1 node/block, 256 threads
    int c2 = threadIdx.x * 2;              // 2 ch/thread -> 512
    float di = dis[node];
    int cnt = slotcnt[node]; cnt = cnt < CAP ? cnt : CAP;
    float w = di * di;
    unsigned int p = *(const unsigned int*)&h[(size_t)node * D2 + c2];
    float a0 = w * bf2f((ushort_t)(p & 0xffffu));
    float a1 = w * bf2f((ushort_t)(p >> 16));
    for (int k = 0; k < cnt; k++) {
        int s = slots[node * CAP + k];
        float ws = dis[s] * di;
        unsigned int q = *(const unsigned int*)&h[(size_t)s * D2 + c2];
        a0 += ws * bf2f((ushort_t)(q & 0xffffu));
        a1 += ws * bf2f((ushort_t)(q >> 16));
    }
    unsigned int o = (unsigned int)f2bf(a0) | ((unsigned int)f2bf(a1) << 16);
    *(unsigned int*)&out[(size_t)node * D2 + c2] = o;
}

// ---------------- MFMA bf16 GEMM:  C = relu(A @ B + bias) ----------------
__global__ __launch_bounds__(256) void k_gemm(const ushort_t* A, const ushort_t* Bt,
                                              const float* bias, ushort_t* Cmat,
                                              int K, int Ncols) {
    __shared__ __align__(16) ushort_t As[128 * 32];
    __shared__ __align__(16) ushort_t Bs[128 * 32];
    int tid = threadIdx.x;
    int bm0 = blockIdx.x * 128, bn0 = blockIdx.y * 128;
    int wave = tid >> 6, lane = tid & 63;
    int wm = (wave & 1) * 64, wn = (wave >> 1) * 64;
    int l15 = lane & 15, quad = lane >> 4;

    f32x4 acc[4][4];
    for (int a = 0; a < 4; a++)
        for (int b = 0; b < 4; b++)
            acc[a][b] = (f32x4){0.f, 0.f, 0.f, 0.f};

    int m1 = tid >> 2, k1 = (tid & 3) << 3;
    int m2 = (tid + 256) >> 2, k2 = ((tid + 256) & 3) << 3;

    for (int kt = 0; kt < K; kt += 32) {
        *(uint4*)&As[m1 * 32 + k1] = *(const uint4*)&A[(size_t)(bm0 + m1) * K + kt + k1];
        *(uint4*)&As[m2 * 32 + k2] = *(const uint4*)&A[(size_t)(bm0 + m2) * K + kt + k2];
        *(uint4*)&Bs[m1 * 32 + k1] = *(const uint4*)&Bt[(size_t)(bn0 + m1) * K + kt + k1];
        *(uint4*)&Bs[m2 * 32 + k2] = *(const uint4*)&Bt[(size_t)(bn0 + m2) * K + kt + k2];
        __syncthreads();

        short8 af[4], bfr[4];
        for (int im = 0; im < 4; im++)
            af[im] = *(const short8*)&As[(wm + im * 16 + l15) * 32 + quad * 8];
        for (int in = 0; in < 4; in++)
            bfr[in] = *(const short8*)&Bs[(wn + in * 16 + l15) * 32 + quad * 8];
        for (int im = 0; im < 4; im++)
            for (int in = 0; in < 4; in++)
                acc[im][in] = __builtin_amdgcn_mfma_f32_16x16x32_bf16(af[im], bfr[in], acc[im][in], 0, 0, 0);
        __syncthreads();
    }

    // epilogue: C/D layout col=lane&15, row=quad*4+r  [m89-verified]
    for (int im = 0; im < 4; im++) {
        int row = bm0 + wm + im * 16 + quad * 4;
        for (int in = 0; in < 4; in++) {
            int col = bn0 + wn + in * 16 + l15;
            float bv = bias[col];
            for (int r = 0; r < 4; r++) {
                float v = acc[im][in][r] + bv;
                v = v > 0.0f ? v : 0.0f;
                Cmat[(size_t)(row + r) * Ncols + col] = f2bf(v);
            }
        }
    }
}

// ---------------- GEMM2 with fused mean-pool accumulation ----------------
__global__ __launch_bounds__(256) void k_gemm_pool(const ushort_t* A, const ushort_t* Bt,
                                                   const float* bias, const int* batch,
                                                   float* pooled, int K) {
    __shared__ __align__(16) ushort_t As[128 * 32];
    __shared__ __align__(16) ushort_t Bs[128 * 32];
    __shared__ float pl[NGRAPH * 128];
    __shared__ int gtile[128];
    int tid = threadIdx.x;
    int bm0 = blockIdx.x * 128, bn0 = blockIdx.y * 128;
    int wave = tid >> 6, lane = tid & 63;
    int wm = (wave & 1) * 64, wn = (wave >> 1) * 64;
    int l15 = lane & 15, quad = lane >> 4;

    for (int i = tid; i < NGRAPH * 128; i += 256) pl[i] = 0.0f;
    if (tid < 128) {
        int r = bm0 + tid; if (r > N_NODES - 1) r = N_NODES - 1;
        int g = batch[r]; g = g < 0 ? 0 : (g > NGRAPH - 1 ? NGRAPH - 1 : g);
        gtile[tid] = g;
    }

    f32x4 acc[4][4];
    for (int a = 0; a < 4; a++)
        for (int b = 0; b < 4; b++)
            acc[a][b] = (f32x4){0.f, 0.f, 0.f, 0.f};

    int m1 = tid >> 2, k1 = (tid & 3) << 3;
    int m2 = (tid + 256) >> 2, k2 = ((tid + 256) & 3) << 3;

    for (int kt = 0; kt < K; kt += 32) {
        *(uint4*)&As[m1 * 32 + k1] = *(const uint4*)&A[(size_t)(bm0 + m1) * K + kt + k1];
        *(uint4*)&As[m2 * 32 + k2] = *(const uint4*)&A[(size_t)(bm0 + m2) * K + kt + k2];
        *(uint4*)&Bs[m1 * 32 + k1] = *(const uint4*)&Bt[(size_t)(bn0 + m1) * K + kt + k1];
        *(uint4*)&Bs[m2 * 32 + k2] = *(const uint4*)&Bt[(size_t)(bn0 + m2) * K + kt + k2];
        __syncthreads();

        short8 af[4], bfr[4];
        for (int im = 0; im < 4; im++)
            af[im] = *(const short8*)&As[(wm + im * 16 + l15) * 32 + quad * 8];
        for (int in = 0; in < 4; in++)
            bfr[in] = *(const short8*)&Bs[(wn + in * 16 + l15) * 32 + quad * 8];
        for (int im = 0; im < 4; im++)
            for (int in = 0; in < 4; in++)
                acc[im][in] = __builtin_amdgcn_mfma_f32_16x16x32_bf16(af[im], bfr[in], acc[im][in], 0, 0, 0);
        __syncthreads();
    }

    for (int im = 0; im < 4; im++) {
        int rl = wm + im * 16 + quad * 4;
        for (int in = 0; in < 4; in++) {
            int cl = wn + in * 16 + l15;
            float bv = bias[bn0 + cl];
            float vsum = 0.0f;
            int gprev = gtile[rl];
            for (int r = 0; r < 4; r++) {
                int row = bm0 + rl + r;
                float v = (row < N_NODES) ? fmaxf(acc[im][in][r] + bv, 0.0f) : 0.0f;
                int g = gtile[rl + r];
                if (g != gprev) {
                    atomicAdd(&pl[gprev * 128 + cl], vsum);
                    vsum = 0.0f; gprev = g;
                }
                vsum += v;
            }
            atomicAdd(&pl[gprev * 128 + cl], vsum);
        }
    }
    __syncthreads();

    int gmin = gtile[0], gmax = gtile[127];
    int span = (gmax - gmin + 1) * 128;
    for (int idx = tid; idx < span; idx += 256) {
        int g = gmin + (idx >> 7), cl = idx & 127;
        float v = pl[g * 128 + cl];
        if (v != 0.0f) atomicAdd(&pooled[g * DOUT + bn0 + cl], v);
    }
}

// ---------------- tail ----------------
__global__ void k_pooldiv(float* pooled, const float* cntg) {
    int i = blockIdx.x * 256 + threadIdx.x;
    if (i >= NGRAPH * DOUT) return;
    int g = i >> 10;
    float c = cntg[g]; c = c > 1.0f ? c : 1.0f;
    pooled[i] = pooled[i] / c;
}

// out[g][o] = pooled[g] . Wo[:,o] + bo[o]; output format per flags[0]
__global__ void k_out(const float* pooled, const float* Wof, const float* bof,
                      void* out, const int* flags) {
    int g = blockIdx.x;
    int o = blockIdx.y * 256 + threadIdx.x;
    float acc = bof[o];
    const float* pr = pooled + g * D3;
    for (int k = 0; k < D3; k++)
        acc += pr[k] * Wof[(size_t)k * DOUT + o];
    size_t idx = (size_t)g * DOUT + o;
    if (flags[0]) ((ushort_t*)out)[idx] = f2bf(acc);
    else          ((float*)out)[idx] = acc;
}

// ---------------- launch ----------------
extern "C" void kernel_launch(void* const* d_in, const int* in_sizes, int n_in,
                              void* d_out, int out_size, void* d_ws, size_t ws_size,
                              hipStream_t stream) {
    const void* x_raw  = d_in[0];
    const void* ei_raw = d_in[1];
    const void* b_raw  = d_in[2];
    const void* W1_raw = d_in[3];
    const void* b1_raw = d_in[4];
    const void* W2_raw = d_in[5];
    const void* b2_raw = d_in[6];
    const void* W3_raw = d_in[7];
    const void* b3_raw = d_in[8];
    const void* Wo_raw = d_in[9];
    const void* bo_raw = d_in[10];

    char* w = (char*)d_ws;
    size_t off = 0;
    auto alloc = [&](size_t b) { size_t o = off; off += (b + 255) & ~(size_t)255; return o; };
    int*   flags   = (int*)  (w + alloc(256));
    float* xf      = (float*)(w + alloc((size_t)N_NODES * 4));
    int*   ei32    = (int*)  (w + alloc((size_t)2 * E_EDGES * 4));   // [src | dst]
    int*   batch32 = (int*)  (w + alloc((size_t)N_NODES * 4));
    float* W1f     = (float*)(w + alloc(D1 * 4));
    float* b1f     = (float*)(w + alloc(D1 * 4));
    float* b2f     = (float*)(w + alloc(D2 * 4));
    float* b3f     = (float*)(w + alloc(D3 * 4));
    float* Wof     = (float*)(w + alloc((size_t)D3 * DOUT * 4));
    float* bof     = (float*)(w + alloc(DOUT * 4));
    float* dis     = (float*)(w + alloc((size_t)N_NODES * 4));
    float* s1      = (float*)(w + alloc((size_t)N_NODES * 4));
    float* cntg    = (float*)(w + alloc(64));
    float* pooled  = (float*)(w + alloc((size_t)NGRAPH * DOUT * 4));
    int*   slotcnt = (int*)  (w + alloc((size_t)N_NODES * 4));
    int*   slots   = (int*)  (w + alloc((size_t)N_NODES * CAP * 4));
    ushort_t* Wt2  = (ushort_t*)(w + alloc((size_t)D2 * D1 * 2));
    ushort_t* Wt3  = (ushort_t*)(w + alloc((size_t)D3 * D2 * 2));
    ushort_t* slabA = (ushort_t*)(w + alloc((size_t)M_PAD * D2 * 2));
    ushort_t* a2 = slabA;       // M_PAD x 256, dies after k_gemm
    ushort_t* a3 = slabA;       // M_PAD x 512, reuses slab
    ushort_t* h2   = (ushort_t*)(w + alloc((size_t)M_PAD * D2 * 2));

    int nb_n = (N_NODES + 255) / 256;
    int nb_e = (E_EDGES + 255) / 256;

    k_detect<<<1, 64, 0, stream>>>(W1_raw, ei_raw, flags);

    // canonicalize inputs
    k_cvt_f32<<<nb_n, 256, 0, stream>>>(x_raw, xf, N_NODES, flags);
    k_cvt_idx<<<(2 * E_EDGES + 255) / 256, 256, 0, stream>>>(ei_raw, ei32, 2 * E_EDGES, flags);
    k_cvt_idx<<<nb_n, 256, 0, stream>>>(b_raw, batch32, N_NODES, flags);
    k_cvt_small<<<12, 256, 0, stream>>>(W1_raw, b1_raw, b2_raw, b3_raw, bo_raw,
                                        W1f, b1f, b2f, b3f, bof, flags);
    k_cvt_f32<<<(D3 * DOUT + 255) / 256, 256, 0, stream>>>(Wo_raw, Wof, D3 * DOUT, flags);
    k_transpose_cvt<<<dim3(D2 / 32, D1 / 32), dim3(32, 8), 0, stream>>>(W2_raw, Wt2, D1, D2, flags);
    k_transpose_cvt<<<dim3(D3 / 32, D2 / 32), dim3(32, 8), 0, stream>>>(W3_raw, Wt3, D2, D3, flags);

    // graph preprocessing (atomics only on 30000-way-spread slotcnt)
    k_init<<<nb_n, 256, 0, stream>>>(slotcnt, pooled);
    k_edge_count<<<nb_e, 256, 0, stream>>>(ei32, ei32 + E_EDGES, slotcnt, slots);
    k_node<<<nb_n, 256, 0, stream>>>(slotcnt, dis);
    k_cnt<<<1, 64, 0, stream>>>(batch32, cntg);
    k_s1<<<nb_n, 256, 0, stream>>>(xf, dis, slots, slotcnt, s1);

    // layer pipeline
    k_agg1<<<N_NODES / 2, 256, 0, stream>>>(s1, W1f, b1f, a2, slots, slotcnt, dis);
    k_gemm<<<dim3(M_PAD / 128, D2 / 128), 256, 0, stream>>>(a2, Wt2, b2f, h2, D1, D2);
    k_agg2<<<N_NODES, 256, 0, stream>>>(h2, a3, slots, slotcnt, dis);
    k_gemm_pool<<<dim3(M_PAD / 128, D3 / 128), 256, 0, stream>>>(a3, Wt3, b3f, batch32, pooled, D2);

    k_pooldiv<<<(NGRAPH * DOUT + 255) / 256, 256, 0, stream>>>(pooled, cntg);
    k_out<<<dim3(NGRAPH, DOUT / 256), 256, 0, stream>>>(pooled, Wof, bof, d_out, flags);
}

// Round 5
// 369.217 us; speedup vs baseline: 2.0928x; 1.0061x over previous
//
#include <hip/hip_runtime.h>
#include <hip/hip_bf16.h>
#include <stdint.h>

// Problem constants (from reference)
#define N_NODES 30000
#define E_EDGES 240000
#define NGRAPH  16
#define D1      256
#define D2      512
#define D3      1024
#define DOUT    1024
#define M_PAD   30080   // 235 * 128, padded row count for GEMM tiles
#define CAP     40      // max in-degree (Poisson(8): P(>=40) negligible)

typedef unsigned short ushort_t;
typedef short short8 __attribute__((ext_vector_type(8)));
typedef float f32x4 __attribute__((ext_vector_type(4)));

#define AS_GLOBAL(p) ((const __attribute__((address_space(1))) void*)(p))
#define AS_LDS(p)    ((__attribute__((address_space(3))) void*)(p))

__device__ __forceinline__ float bf2f(ushort_t u) {
    union { unsigned int i; float f; } v; v.i = ((unsigned int)u) << 16; return v.f;
}
__device__ __forceinline__ ushort_t f2bf(float x) {
    union { float f; unsigned int i; } v; v.f = x;
    unsigned int r = v.i + 0x7fffu + ((v.i >> 16) & 1u);   // RNE
    return (ushort_t)(r >> 16);
}

// ---------------- runtime dtype detection ----------------
__global__ void k_detect(const void* w1, const void* ei, int* flags) {
    if (threadIdx.x != 0 || blockIdx.x != 0) return;
    const ushort_t* h = (const ushort_t*)w1;
    int isbf16 = 1;
    for (int i = 0; i < 128; i += 2) {
        float v = fabsf(bf2f(h[i]));
        if (!(v <= 0.25f)) { isbf16 = 0; break; }
    }
    const int* e = (const int*)ei;
    int isi64 = 1;
    for (int i = 1; i < 128; i += 2) {
        if (e[i] != 0) { isi64 = 0; break; }
    }
    flags[0] = isbf16;
    flags[1] = isi64;
}

// ---------------- canonicalization ----------------
__global__ void k_cvt_f32(const void* in, float* out, int n, const int* flags) {
    int i = blockIdx.x * 256 + threadIdx.x;
    if (i >= n) return;
    out[i] = flags[0] ? bf2f(((const ushort_t*)in)[i]) : ((const float*)in)[i];
}

__global__ void k_cvt_idx(const void* in, int* out, int n, const int* flags) {
    int i = blockIdx.x * 256 + threadIdx.x;
    if (i >= n) return;
    out[i] = flags[1] ? (int)((const long long*)in)[i] : ((const int*)in)[i];
}

// merged small-array conversion: W1(256), b1(256), b2(512), b3(1024), bo(1024)
__global__ void k_cvt_small(const void* w1, const void* b1, const void* b2,
                            const void* b3, const void* bo,
                            float* W1f, float* b1f, float* b2f, float* b3f, float* bof,
                            const int* flags) {
    int i = blockIdx.x * 256 + threadIdx.x;
    const void* src; float* dst; int idx;
    if      (i < 256)  { src = w1; dst = W1f; idx = i; }
    else if (i < 512)  { src = b1; dst = b1f; idx = i - 256; }
    else if (i < 1024) { src = b2; dst = b2f; idx = i - 512; }
    else if (i < 2048) { src = b3; dst = b3f; idx = i - 1024; }
    else               { src = bo; dst = bof; idx = i - 2048; }
    dst[idx] = flags[0] ? bf2f(((const ushort_t*)src)[idx]) : ((const float*)src)[idx];
}

// transpose (R x C -> C x R) + convert to bf16; dims multiples of 32
__global__ void k_transpose_cvt(const void* in, ushort_t* out, int R, int C, const int* flags) {
    __shared__ ushort_t tile[32][33];
    int tx = threadIdx.x, ty = threadIdx.y;
    int c0 = blockIdx.x * 32, r0 = blockIdx.y * 32;
    int isbf = flags[0];
    for (int i = ty; i < 32; i += 8) {
        size_t idx = (size_t)(r0 + i) * C + c0 + tx;
        tile[i][tx] = isbf ? ((const ushort_t*)in)[idx] : f2bf(((const float*)in)[idx]);
    }
    __syncthreads();
    for (int i = ty; i < 32; i += 8) out[(size_t)(c0 + i) * R + r0 + tx] = tile[tx][i];
}

// ---------------- setup kernels ----------------
__global__ void k_init(int* slotcnt, float* pooled) {
    int i = blockIdx.x * 256 + threadIdx.x;
    if (i < N_NODES) slotcnt[i] = 0;
    if (i < NGRAPH * DOUT) pooled[i] = 0.0f;
}

__global__ void k_edge_count(const int* eis, const int* eid, int* slotcnt, int* slots) {
    int e = blockIdx.x * 256 + threadIdx.x;
    if (e >= E_EDGES) return;
    int s = eis[e], d = eid[e];
    if ((unsigned)s >= N_NODES || (unsigned)d >= N_NODES) return;
    int pos = atomicAdd(&slotcnt[d], 1);
    if (pos < CAP) slots[d * CAP + pos] = s;
}

__global__ void k_node(const int* slotcnt, float* dis) {
    int i = blockIdx.x * 256 + threadIdx.x;
    if (i >= N_NODES) return;
    dis[i] = rsqrtf(1.0f + (float)slotcnt[i]);
}

// graph node counts via binary search on sorted batch (zero atomics)
__global__ void k_cnt(const int* batch, float* cntg) {
    int g = threadIdx.x;
    if (g >= NGRAPH) return;
    int lo0 = 0, hi0 = N_NODES;
    while (lo0 < hi0) { int m = (lo0 + hi0) >> 1; if (batch[m] < g) lo0 = m + 1; else hi0 = m; }
    int lo1 = lo0, hi1 = N_NODES;
    while (lo1 < hi1) { int m = (lo1 + hi1) >> 1; if (batch[m] < g + 1) lo1 = m + 1; else hi1 = m; }
    cntg[g] = (float)(lo1 - lo0);
}

// s1[d] = x[d]*dis[d]^2 + dis[d] * sum_s x[s]*dis[s]
__global__ void k_s1(const float* xf, const float* dis, const int* slots,
                     const int* slotcnt, float* s1) {
    int d = blockIdx.x * 256 + threadIdx.x;
    if (d >= N_NODES) return;
    float di = dis[d];
    int cnt = slotcnt[d]; cnt = cnt < CAP ? cnt : CAP;
    float acc = xf[d] * di;
    for (int k = 0; k < cnt; k++) {
        int s = slots[d * CAP + k];
        acc += xf[s] * dis[s];
    }
    s1[d] = acc * di;
}

// ---------------- fused layer-1 + layer-2 aggregation ----------------
__global__ void k_agg1(const float* s1, const float* W1f, const float* b1f,
                       ushort_t* a2, const int* slots, const int* slotcnt, const float* dis) {
    int node = blockIdx.x * 2 + (threadIdx.x >> 7);
    int c2 = (threadIdx.x & 127) * 2;
    if (node >= N_NODES) return;
    float w0 = W1f[c2], w1 = W1f[c2 + 1];
    float bb0 = b1f[c2], bb1 = b1f[c2 + 1];
    float di = dis[node];
    int cnt = slotcnt[node]; cnt = cnt < CAP ? cnt : CAP;
    float sv = s1[node];
    float wsl = di * di;
    float a0 = wsl * fmaxf(sv * w0 + bb0, 0.0f);
    float a1 = wsl * fmaxf(sv * w1 + bb1, 0.0f);
    for (int k = 0; k < cnt; k++) {
        int s = slots[node * CAP + k];
        float ss = s1[s];
        float wn = dis[s] * di;
        a0 += wn * fmaxf(ss * w0 + bb0, 0.0f);
        a1 += wn * fmaxf(ss * w1 + bb1, 0.0f);
    }
    unsigned int o = (unsigned int)f2bf(a0) | ((unsigned int)f2bf(a1) << 16);
    *(unsigned int*)&a2[(size_t)node * D1 + c2] = o;
}

// ---------------- layer-3 aggregation: a3 = A_hat * h2  (512 ch) ----------------
__global__ void k_agg2(const ushort_t* h, ushort_t* out, const int* slots,
                       const int* slotcnt, const float* dis) {
    int node = blockIdx.x;
    int c2 = threadIdx.x * 2;
    float di = dis[node];
    int cnt = slotcnt[node]; cnt = cnt < CAP ? cnt : CAP;
    float w = di * di;
    unsigned int p = *(const unsigned int*)&h[(size_t)node * D2 + c2];
    float a0 = w * bf2f((ushort_t)(p & 0xffffu));
    float a1 = w * bf2f((ushort_t)(p >> 16));
    for (int k = 0; k < cnt; k++) {
        int s = slots[node * CAP + k];
        float ws = dis[s] * di;
        unsigned int q = *(const unsigned int*)&h[(size_t)s * D2 + c2];
        a0 += ws * bf2f((ushort_t)(q & 0xffffu));
        a1 += ws * bf2f((ushort_t)(q >> 16));
    }
    unsigned int o = (unsigned int)f2bf(a0) | ((unsigned int)f2bf(a1) << 16);
    *(unsigned int*)&out[(size_t)node * D2 + c2] = o;
}

// ---------------- MFMA bf16 GEMM with async LDS staging ----------------
// Grid: x = N tile (fastest, for A-panel L2 reuse), y = M tile.
// Staging: each wave issues 4x global_load_lds(16B): 2 chunks of A, 2 of B.
// Chunk = 1KB = 16 rows x 32 ushorts; lane i -> row wave*32+(i>>2)+{0,16}, kofs (i&3)*8.
// LDS dest = wave-uniform base + lane*16B (m104/m108 rule) == row-major [128][32].
__global__ __launch_bounds__(256) void k_gemm(const ushort_t* A, const ushort_t* Bt,
                                              const float* bias, ushort_t* Cmat,
                                              int K, int Ncols) {
    __shared__ __align__(16) ushort_t As[128 * 32];
    __shared__ __align__(16) ushort_t Bs[128 * 32];
    int tid = threadIdx.x;
    int bn0 = blockIdx.x * 128, bm0 = blockIdx.y * 128;
    int wave = tid >> 6, lane = tid & 63;
    int wm = (wave & 1) * 64, wn = (wave >> 1) * 64;
    int l15 = lane & 15, quad = lane >> 4;

    f32x4 acc[4][4];
    for (int a = 0; a < 4; a++)
        for (int b = 0; b < 4; b++)
            acc[a][b] = (f32x4){0.f, 0.f, 0.f, 0.f};

    int srow = wave * 32 + (lane >> 2);
    int skofs = (lane & 3) << 3;
    const ushort_t* gA = A + (size_t)(bm0 + srow) * K + skofs;
    const ushort_t* gB = Bt + (size_t)(bn0 + srow) * K + skofs;
    ushort_t* lA = &As[wave * 1024];
    ushort_t* lB = &Bs[wave * 1024];

    for (int kt = 0; kt < K; kt += 32) {
        __builtin_amdgcn_global_load_lds(AS_GLOBAL(gA + kt), AS_LDS(lA), 16, 0, 0);
        __builtin_amdgcn_global_load_lds(AS_GLOBAL(gA + kt + (size_t)16 * K), AS_LDS(lA + 512), 16, 0, 0);
        __builtin_amdgcn_global_load_lds(AS_GLOBAL(gB + kt), AS_LDS(lB), 16, 0, 0);
        __builtin_amdgcn_global_load_lds(AS_GLOBAL(gB + kt + (size_t)16 * K), AS_LDS(lB + 512), 16, 0, 0);
        __syncthreads();

        short8 af[4], bfr[4];
        for (int im = 0; im < 4; im++)
            af[im] = *(const short8*)&As[(wm + im * 16 + l15) * 32 + quad * 8];
        for (int in = 0; in < 4; in++)
            bfr[in] = *(const short8*)&Bs[(wn + in * 16 + l15) * 32 + quad * 8];
        for (int im = 0; im < 4; im++)
            for (int in = 0; in < 4; in++)
                acc[im][in] = __builtin_amdgcn_mfma_f32_16x16x32_bf16(af[im], bfr[in], acc[im][in], 0, 0, 0);
        __syncthreads();
    }

    // epilogue: C/D layout col=lane&15, row=quad*4+r  [m89-verified]
    for (int im = 0; im < 4; im++) {
        int row = bm0 + wm + im * 16 + quad * 4;
        for (int in = 0; in < 4; in++) {
            int col = bn0 + wn + in * 16 + l15;
            float bv = bias[col];
            for (int r = 0; r < 4; r++) {
                float v = acc[im][in][r] + bv;
                v = v > 0.0f ? v : 0.0f;
                Cmat[(size_t)(row + r) * Ncols + col] = f2bf(v);
            }
        }
    }
}

// ---------------- GEMM2 with fused mean-pool accumulation ----------------
__global__ __launch_bounds__(256) void k_gemm_pool(const ushort_t* A, const ushort_t* Bt,
                                                   const float* bias, const int* batch,
                                                   float* pooled, int K) {
    __shared__ __align__(16) ushort_t As[128 * 32];
    __shared__ __align__(16) ushort_t Bs[128 * 32];
    __shared__ float pl[NGRAPH * 128];
    __shared__ int gtile[128];
    int tid = threadIdx.x;
    int bn0 = blockIdx.x * 128, bm0 = blockIdx.y * 128;
    int wave = tid >> 6, lane = tid & 63;
    int wm = (wave & 1) * 64, wn = (wave >> 1) * 64;
    int l15 = lane & 15, quad = lane >> 4;

    for (int i = tid; i < NGRAPH * 128; i += 256) pl[i] = 0.0f;
    if (tid < 128) {
        int r = bm0 + tid; if (r > N_NODES - 1) r = N_NODES - 1;
        int g = batch[r]; g = g < 0 ? 0 : (g > NGRAPH - 1 ? NGRAPH - 1 : g);
        gtile[tid] = g;
    }

    f32x4 acc[4][4];
    for (int a = 0; a < 4; a++)
        for (int b = 0; b < 4; b++)
            acc[a][b] = (f32x4){0.f, 0.f, 0.f, 0.f};

    int srow = wave * 32 + (lane >> 2);
    int skofs = (lane & 3) << 3;
    const ushort_t* gA = A + (size_t)(bm0 + srow) * K + skofs;
    const ushort_t* gB = Bt + (size_t)(bn0 + srow) * K + skofs;
    ushort_t* lA = &As[wave * 1024];
    ushort_t* lB = &Bs[wave * 1024];

    for (int kt = 0; kt < K; kt += 32) {
        __builtin_amdgcn_global_load_lds(AS_GLOBAL(gA + kt), AS_LDS(lA), 16, 0, 0);
        __builtin_amdgcn_global_load_lds(AS_GLOBAL(gA + kt + (size_t)16 * K), AS_LDS(lA + 512), 16, 0, 0);
        __builtin_amdgcn_global_load_lds(AS_GLOBAL(gB + kt), AS_LDS(lB), 16, 0, 0);
        __builtin_amdgcn_global_load_lds(AS_GLOBAL(gB + kt + (size_t)16 * K), AS_LDS(lB + 512), 16, 0, 0);
        __syncthreads();

        short8 af[4], bfr[4];
        for (int im = 0; im < 4; im++)
            af[im] = *(const short8*)&As[(wm + im * 16 + l15) * 32 + quad * 8];
        for (int in = 0; in < 4; in++)
            bfr[in] = *(const short8*)&Bs[(wn + in * 16 + l15) * 32 + quad * 8];
        for (int im = 0; im < 4; im++)
            for (int in = 0; in < 4; in++)
                acc[im][in] = __builtin_amdgcn_mfma_f32_16x16x32_bf16(af[im], bfr[in], acc[im][in], 0, 0, 0);
        __syncthreads();
    }

    // epilogue: bias + relu, reduce rows by graph into LDS pool table
    for (int im = 0; im < 4; im++) {
        int rl = wm + im * 16 + quad * 4;
        for (int in = 0; in < 4; in++) {
            int cl = wn + in * 16 + l15;
            float bv = bias[bn0 + cl];
            float vsum = 0.0f;
            int gprev = gtile[rl];
            for (int r = 0; r < 4; r++) {
                int row = bm0 + rl + r;
                float v = (row < N_NODES) ? fmaxf(acc[im][in][r] + bv, 0.0f) : 0.0f;
                int g = gtile[rl + r];
                if (g != gprev) {
                    atomicAdd(&pl[gprev * 128 + cl], vsum);
                    vsum = 0.0f; gprev = g;
                }
                vsum += v;
            }
            atomicAdd(&pl[gprev * 128 + cl], vsum);
        }
    }
    __syncthreads();

    int gmin = gtile[0], gmax = gtile[127];
    int span = (gmax - gmin + 1) * 128;
    for (int idx = tid; idx < span; idx += 256) {
        int g = gmin + (idx >> 7), cl = idx & 127;
        float v = pl[g * 128 + cl];
        if (v != 0.0f) atomicAdd(&pooled[g * DOUT + bn0 + cl], v);
    }
}

// ---------------- tail: out[g][o] = (pooled[g]@Wo)[o]/cnt + bo[o] ----------------
__global__ void k_out(const float* pooled, const float* Wof, const float* bof,
                      const float* cntg, void* out, const int* flags) {
    int g = blockIdx.x;
    int o = blockIdx.y * 256 + threadIdx.x;
    float dot = 0.0f;
    const float* pr = pooled + g * D3;
    for (int k = 0; k < D3; k++)
        dot += pr[k] * Wof[(size_t)k * DOUT + o];
    float c = cntg[g]; c = c > 1.0f ? c : 1.0f;
    float acc = dot / c + bof[o];
    size_t idx = (size_t)g * DOUT + o;
    if (flags[0]) ((ushort_t*)out)[idx] = f2bf(acc);
    else          ((float*)out)[idx] = acc;
}

// ---------------- launch ----------------
extern "C" void kernel_launch(void* const* d_in, const int* in_sizes, int n_in,
                              void* d_out, int out_size, void* d_ws, size_t ws_size,
                              hipStream_t stream) {
    const void* x_raw  = d_in[0];
    const void* ei_raw = d_in[1];
    const void* b_raw  = d_in[2];
    const void* W1_raw = d_in[3];
    const void* b1_raw = d_in[4];
    const void* W2_raw = d_in[5];
    const void* b2_raw = d_in[6];
    const void* W3_raw = d_in[7];
    const void* b3_raw = d_in[8];
    const void* Wo_raw = d_in[9];
    const void* bo_raw = d_in[10];

    char* w = (char*)d_ws;
    size_t off = 0;
    auto alloc = [&](size_t b) { size_t o = off; off += (b + 255) & ~(size_t)255; return o; };
    int*   flags   = (int*)  (w + alloc(256));
    float* xf      = (float*)(w + alloc((size_t)N_NODES * 4));
    int*   ei32    = (int*)  (w + alloc((size_t)2 * E_EDGES * 4));
    int*   batch32 = (int*)  (w + alloc((size_t)N_NODES * 4));
    float* W1f     = (float*)(w + alloc(D1 * 4));
    float* b1f     = (float*)(w + alloc(D1 * 4));
    float* b2f     = (float*)(w + alloc(D2 * 4));
    float* b3f     = (float*)(w + alloc(D3 * 4));
    float* Wof     = (float*)(w + alloc((size_t)D3 * DOUT * 4));
    float* bof     = (float*)(w + alloc(DOUT * 4));
    float* dis     = (float*)(w + alloc((size_t)N_NODES * 4));
    float* s1      = (float*)(w + alloc((size_t)N_NODES * 4));
    float* cntg    = (float*)(w + alloc(64));
    float* pooled  = (float*)(w + alloc((size_t)NGRAPH * DOUT * 4));
    int*   slotcnt = (int*)  (w + alloc((size_t)N_NODES * 4));
    int*   slots   = (int*)  (w + alloc((size_t)N_NODES * CAP * 4));
    ushort_t* Wt2  = (ushort_t*)(w + alloc((size_t)D2 * D1 * 2));
    ushort_t* Wt3  = (ushort_t*)(w + alloc((size_t)D3 * D2 * 2));
    ushort_t* slabA = (ushort_t*)(w + alloc((size_t)M_PAD * D2 * 2));
    ushort_t* a2 = slabA;       // M_PAD x 256, dies after k_gemm
    ushort_t* a3 = slabA;       // M_PAD x 512, reuses slab
    ushort_t* h2   = (ushort_t*)(w + alloc((size_t)M_PAD * D2 * 2));

    int nb_n = (N_NODES + 255) / 256;
    int nb_e = (E_EDGES + 255) / 256;

    k_detect<<<1, 64, 0, stream>>>(W1_raw, ei_raw, flags);

    // canonicalize inputs
    k_cvt_f32<<<nb_n, 256, 0, stream>>>(x_raw, xf, N_NODES, flags);
    k_cvt_idx<<<(2 * E_EDGES + 255) / 256, 256, 0, stream>>>(ei_raw, ei32, 2 * E_EDGES, flags);
    k_cvt_idx<<<nb_n, 256, 0, stream>>>(b_raw, batch32, N_NODES, flags);
    k_cvt_small<<<12, 256, 0, stream>>>(W1_raw, b1_raw, b2_raw, b3_raw, bo_raw,
                                        W1f, b1f, b2f, b3f, bof, flags);
    k_cvt_f32<<<(D3 * DOUT + 255) / 256, 256, 0, stream>>>(Wo_raw, Wof, D3 * DOUT, flags);
    k_transpose_cvt<<<dim3(D2 / 32, D1 / 32), dim3(32, 8), 0, stream>>>(W2_raw, Wt2, D1, D2, flags);
    k_transpose_cvt<<<dim3(D3 / 32, D2 / 32), dim3(32, 8), 0, stream>>>(W3_raw, Wt3, D2, D3, flags);

    // graph preprocessing
    k_init<<<nb_n, 256, 0, stream>>>(slotcnt, pooled);
    k_edge_count<<<nb_e, 256, 0, stream>>>(ei32, ei32 + E_EDGES, slotcnt, slots);
    k_node<<<nb_n, 256, 0, stream>>>(slotcnt, dis);
    k_cnt<<<1, 64, 0, stream>>>(batch32, cntg);
    k_s1<<<nb_n, 256, 0, stream>>>(xf, dis, slots, slotcnt, s1);

    // layer pipeline
    k_agg1<<<N_NODES / 2, 256, 0, stream>>>(s1, W1f, b1f, a2, slots, slotcnt, dis);
    k_gemm<<<dim3(D2 / 128, M_PAD / 128), 256, 0, stream>>>(a2, Wt2, b2f, h2, D1, D2);
    k_agg2<<<N_NODES, 256, 0, stream>>>(h2, a3, slots, slotcnt, dis);
    k_gemm_pool<<<dim3(D3 / 128, M_PAD / 128), 256, 0, stream>>>(a3, Wt3, b3f, batch32, pooled, D2);

    k_out<<<dim3(NGRAPH, DOUT / 256), 256, 0, stream>>>(pooled, Wof, bof, cntg, d_out, flags);
}